// Round 5
// baseline (315.105 us; speedup 1.0000x reference)
//
#include <hip/hip_runtime.h>
#include <hip/hip_bf16.h>

#define C_IN  64
#define C_OUT 128
#define KK    27
#define HH    100000
#define TB    1563         // transpose blocks = ceil(HH/64)
#define WB    108          // weight-convert blocks (108*2048 = 221184 elems)
#define BH    96           // h per block (2 waves x 48)
#define NBLK  1042         // ceil(HH/96)

typedef __attribute__((ext_vector_type(8))) short s8v;    // 8 bf16 (MFMA A/B frag)
typedef __attribute__((ext_vector_type(4))) float f32x4;  // MFMA C/D frag

__device__ inline unsigned short f2bf(float f) {
    __hip_bfloat16 h = __float2bfloat16(f);
    return *reinterpret_cast<unsigned short*>(&h);
}

// ---- prep: transpose x -> xt (bf16, [h][64]), W -> wk (bf16, [k][o][c] plain) ----
__global__ __launch_bounds__(256) void prep_kernel(const float* __restrict__ x,
                                                   const float* __restrict__ w,
                                                   unsigned short* __restrict__ xt,
                                                   unsigned short* __restrict__ wk) {
    const int tid = threadIdx.x;
    if (blockIdx.x < TB) {
        __shared__ __align__(16) unsigned short ts[64 * 72];
        const int hbase = blockIdx.x * 64;
        #pragma unroll
        for (int it = 0; it < 16; ++it) {
            int i = it * 256 + tid;           // 64h x 64c
            int c = i >> 6, hl = i & 63;
            int hg = hbase + hl;
            float v = (hg < HH) ? x[(size_t)c * HH + hg] : 0.f;  // coalesced in h
            ts[hl * 72 + c] = f2bf(v);
        }
        __syncthreads();
        #pragma unroll
        for (int it = 0; it < 2; ++it) {
            int u = it * 256 + tid;           // 64 rows x 8 chunks of 16B
            int hl = u >> 3, part = u & 7;
            int hg = hbase + hl;
            if (hg < HH)
                *(int4*)&xt[(size_t)hg * 64 + part * 8] = *(const int4*)&ts[hl * 72 + part * 8];
        }
    } else {
        int b = blockIdx.x - TB;
        int base = b * 2048 + tid;
        #pragma unroll
        for (int j = 0; j < 8; ++j) {
            int t = base + j * 256;           // t = k*8192 + o*64 + c
            int c = t & 63, o = (t >> 6) & 127, kx = t >> 13;
            wk[t] = f2bf(w[(size_t)o * (C_IN * KK) + c * KK + kx]);
        }
    }
}

// ---------------- main gather-GEMM: barrier-free K-loop ----------------
// block 128 thr = 2 waves; wave tile M=128 (all o) x N=48 h.
// A (weights) read directly from global (L1/L2-cached, same slice across waves);
// B (gathered columns) direct global->VGPR with 1-iter ping-pong prefetch.
// NO __syncthreads in the K-loop -> no vmcnt(0) drains; waves free-run.
__global__ __launch_bounds__(128, 2) void conv_main(const unsigned short* __restrict__ xt,
                                                    const unsigned short* __restrict__ wk,
                                                    const int* __restrict__ neigh,
                                                    float* __restrict__ out) {
    __shared__ int neigh_s[BH * KK];                   // 10368 B, [h][k]

    const int tid  = threadIdx.x;
    const int wave = tid >> 6;
    const int lane = tid & 63;
    const int col  = lane & 15;
    const int quad = lane >> 4;
    const int hbase = blockIdx.x * BH;

    // ---- stage neighbor indices (contiguous 10 KB region, fully coalesced) ----
    for (int i = tid; i < BH * KK; i += 128) {
        int hl = i / KK, kx = i - hl * KK;
        int hg = hbase + hl;
        neigh_s[i] = (hg < HH) ? neigh[(size_t)hg * KK + kx] : -1;
    }

    f32x4 acc[8][3];
    #pragma unroll
    for (int mt = 0; mt < 8; ++mt)
        #pragma unroll
        for (int nt = 0; nt < 3; ++nt)
            acc[mt][nt] = (f32x4){0.f, 0.f, 0.f, 0.f};

    __syncthreads();   // the only block barrier: neigh_s visible

    const unsigned short* xq = xt + quad * 8;          // chunk base within a column

    auto loadB = [&](int kk, int4 (&B)[2][3]) {
        #pragma unroll
        for (int nt = 0; nt < 3; ++nt) {
            int n = wave * 48 + nt * 16 + col;
            int idx = neigh_s[n * KK + kk];
            if (idx >= 0) {
                const unsigned short* base = xq + (size_t)idx * 64;
                B[0][nt] = *(const int4*)(base);        // c in [quad*8, quad*8+8)
                B[1][nt] = *(const int4*)(base + 32);   // c in [32+quad*8, ...)
            } else {
                B[0][nt] = make_int4(0, 0, 0, 0);
                B[1][nt] = make_int4(0, 0, 0, 0);
            }
        }
    };

    const unsigned short* wbase = wk + col * 64 + quad * 8;  // lane's A-frag base

    auto mfmaK = [&](int k, int4 (&B)[2][3]) {
        const unsigned short* wp = wbase + (size_t)k * (C_OUT * C_IN);
        #pragma unroll
        for (int ch = 0; ch < 2; ++ch) {
            #pragma unroll
            for (int mt = 0; mt < 8; ++mt) {
                s8v a = *(const s8v*)(wp + mt * 1024 + ch * 32);   // row mt*16+col, k-chunk ch
                #pragma unroll
                for (int nt = 0; nt < 3; ++nt)
                    acc[mt][nt] = __builtin_amdgcn_mfma_f32_16x16x32_bf16(
                        a, __builtin_bit_cast(s8v, B[ch][nt]), acc[mt][nt], 0, 0, 0);
            }
        }
    };

    int4 B0[2][3], B1[2][3];
    loadB(0, B0);

    // 27 = 13*2 + 1; ping-pong B0/B1, zero barriers
    #pragma unroll 1
    for (int kb = 0; kb < 13; ++kb) {
        int k = kb * 2;
        loadB(k + 1, B1);     // prefetch under mfmaK(k)
        mfmaK(k, B0);
        loadB(k + 2, B0);     // kb=12 -> k+2 = 26, in range
        mfmaK(k + 1, B1);
    }
    mfmaK(26, B0);

    // ---- epilogue: D row = quad*4+r (o), col (h); relu + fp32 store ----
    #pragma unroll
    for (int mt = 0; mt < 8; ++mt) {
        #pragma unroll
        for (int nt = 0; nt < 3; ++nt) {
            int hg = hbase + wave * 48 + nt * 16 + col;
            if (hg < HH) {
                #pragma unroll
                for (int r = 0; r < 4; ++r) {
                    int o = mt * 16 + quad * 4 + r;
                    float v = acc[mt][nt][r];
                    out[(size_t)o * HH + hg] = v > 0.f ? v : 0.f;
                }
            }
        }
    }
}

extern "C" void kernel_launch(void* const* d_in, const int* in_sizes, int n_in,
                              void* d_out, int out_size, void* d_ws, size_t ws_size,
                              hipStream_t stream) {
    const float* data_in = (const float*)d_in[0];
    const int*   neigh   = (const int*)d_in[1];
    const float* weight  = (const float*)d_in[2];
    float* out = (float*)d_out;

    unsigned short* xt = (unsigned short*)d_ws;            // H*64 bf16 = 12.8 MB
    unsigned short* wk = xt + (size_t)HH * 64;             // 27*128*64 bf16 = 442 KB

    prep_kernel<<<TB + WB, 256, 0, stream>>>(data_in, weight, xt, wk);
    conv_main<<<NBLK, 128, 0, stream>>>(xt, wk, neigh, out);
}

// Round 6
// 232.709 us; speedup vs baseline: 1.3541x; 1.3541x over previous
//
#include <hip/hip_runtime.h>
#include <hip/hip_bf16.h>

#define C_IN  64
#define C_OUT 128
#define KK    27
#define HH    100000
#define TB    1563         // transpose blocks = ceil(HH/64)
#define WB    108          // weight-convert blocks (108*2048 = 221184 elems)
#define NBLK  391          // ceil(HH/256)

typedef __attribute__((ext_vector_type(8))) short s8v;    // 8 bf16 (MFMA A/B frag)
typedef __attribute__((ext_vector_type(4))) float f32x4;  // MFMA C/D frag

// s_waitcnt lgkmcnt(0) only: vmcnt=63, expcnt=7, lgkmcnt=0 -> 0xC07F (NO vmcnt drain)
#define LGKM0_BARRIER() do { \
    __asm__ __volatile__("" ::: "memory"); \
    __builtin_amdgcn_s_waitcnt(0xC07F); \
    __builtin_amdgcn_s_barrier(); \
    __asm__ __volatile__("" ::: "memory"); \
} while (0)

__device__ inline unsigned short f2bf(float f) {
    __hip_bfloat16 h = __float2bfloat16(f);
    return *reinterpret_cast<unsigned short*>(&h);
}

// ---- prep: transpose x -> xt (bf16, [h][64]), W -> wk (bf16, [k][o][64] XOR-swizzled) ----
// wk physical chunk pj (16B unit) holds logical chunk pj ^ (o&7).
__global__ __launch_bounds__(256) void prep_kernel(const float* __restrict__ x,
                                                   const float* __restrict__ w,
                                                   unsigned short* __restrict__ xt,
                                                   unsigned short* __restrict__ wk) {
    const int tid = threadIdx.x;
    if (blockIdx.x < TB) {
        __shared__ __align__(16) unsigned short ts[64 * 72];
        const int hbase = blockIdx.x * 64;
        #pragma unroll
        for (int it = 0; it < 16; ++it) {
            int i = it * 256 + tid;           // 64h x 64c
            int c = i >> 6, hl = i & 63;
            int hg = hbase + hl;
            float v = (hg < HH) ? x[(size_t)c * HH + hg] : 0.f;  // coalesced in h
            ts[hl * 72 + c] = f2bf(v);
        }
        __syncthreads();
        #pragma unroll
        for (int it = 0; it < 2; ++it) {
            int u = it * 256 + tid;           // 64 rows x 8 chunks of 16B
            int hl = u >> 3, part = u & 7;
            int hg = hbase + hl;
            if (hg < HH)
                *(int4*)&xt[(size_t)hg * 64 + part * 8] = *(const int4*)&ts[hl * 72 + part * 8];
        }
    } else {
        int b = blockIdx.x - TB;
        int base = b * 2048 + tid;
        #pragma unroll
        for (int j = 0; j < 8; ++j) {
            int t = base + j * 256;           // wk index: t = k*8192 + o*64 + jj
            int jj = t & 63, o = (t >> 6) & 127, kx = t >> 13;
            int lc = (jj >> 3) ^ (o & 7);     // logical chunk
            int c  = lc * 8 + (jj & 7);
            wk[t] = f2bf(w[(size_t)o * (C_IN * KK) + c * KK + kx]);
        }
    }
}

// ---------------- main gather-GEMM: raw-barrier pipelined K-loop ----------------
// block 256 thr = 4 waves; wave tile M=128 (all o) x N=64 h.
// W: global->VGPR->ds_write, double-buffered LDS; B: direct global->VGPR, depth-2 ping-pong.
// Barriers are raw s_barrier + lgkmcnt(0) only -> outstanding global loads are NEVER drained.
__global__ __launch_bounds__(256, 2) void conv_main(const unsigned short* __restrict__ xt,
                                                    const unsigned short* __restrict__ wk,
                                                    const int* __restrict__ neigh,
                                                    float* __restrict__ out) {
    __shared__ int neigh_s[256 * KK];                            // 27648 B, [h][k]
    __shared__ __align__(16) unsigned short w_s[2][128 * 64];    // 2 x 16 KB, XOR-swizzled rows

    const int tid  = threadIdx.x;
    const int wave = tid >> 6;
    const int lane = tid & 63;
    const int col  = lane & 15;
    const int quad = lane >> 4;
    const int hbase = blockIdx.x * 256;

    // ---- stage neighbor indices (coalesced; 27*256 exactly) ----
    #pragma unroll
    for (int j = 0; j < KK; ++j) {
        int i = j * 256 + tid;
        int hl = i / KK, kx = i - hl * KK;
        int hg = hbase + hl;
        neigh_s[i] = (hg < HH) ? neigh[(size_t)hg * KK + kx] : -1;
    }

    f32x4 acc[8][4];
    #pragma unroll
    for (int mt = 0; mt < 8; ++mt)
        #pragma unroll
        for (int nt = 0; nt < 4; ++nt)
            acc[mt][nt] = (f32x4){0.f, 0.f, 0.f, 0.f};

    __syncthreads();   // once: neigh_s visible (vmcnt drain acceptable here)

    const unsigned short* xq = xt + quad * 8;   // lane's chunk base within a gathered column

    // W register staging: 16 KB slice / 256 thr = 64 B = 4 int4 per thread (identity copy)
    auto loadW = [&](int k, int4 (&W)[4]) {
        const int4* src = (const int4*)(wk + (size_t)k * (C_OUT * C_IN));
        #pragma unroll
        for (int j = 0; j < 4; ++j) W[j] = src[j * 256 + tid];
    };
    auto writeW = [&](int p, int4 (&W)[4]) {
        #pragma unroll
        for (int j = 0; j < 4; ++j)
            *(int4*)&w_s[p][(j * 256 + tid) * 8] = W[j];
    };

    auto loadB = [&](int kk, int4 (&B)[2][4]) {
        #pragma unroll
        for (int nt = 0; nt < 4; ++nt) {
            int n = wave * 64 + nt * 16 + col;
            int idx = neigh_s[n * KK + kk];
            if (idx >= 0) {
                const unsigned short* base = xq + (size_t)idx * 64;
                B[0][nt] = *(const int4*)(base);        // c in [quad*8, quad*8+8)
                B[1][nt] = *(const int4*)(base + 32);   // c + 32
            } else {
                B[0][nt] = make_int4(0, 0, 0, 0);
                B[1][nt] = make_int4(0, 0, 0, 0);
            }
        }
    };

    auto mfma_phase = [&](const unsigned short* wbuf, int4 (&B)[2][4]) {
        #pragma unroll
        for (int ch = 0; ch < 2; ++ch) {
            const int pc = (ch * 4 + quad) ^ (col & 7);   // XOR-swizzled physical chunk
            #pragma unroll
            for (int mt = 0; mt < 8; ++mt) {
                s8v a = *(const s8v*)&wbuf[(mt * 16 + col) * 64 + pc * 8];
                #pragma unroll
                for (int nt = 0; nt < 4; ++nt)
                    acc[mt][nt] = __builtin_amdgcn_mfma_f32_16x16x32_bf16(
                        a, __builtin_bit_cast(s8v, B[ch][nt]), acc[mt][nt], 0, 0, 0);
            }
        }
    };

    int4 WA[4], WB_[4], B0[2][4], B1[2][4];

    // prologue: W(0)->lds buf0; W(1),B(0),B(1) in flight
    loadW(0, WA);
    loadB(0, B0);
    writeW(0, WA);            // vmcnt waits for WA only (B0 issued after -> stays outstanding)
    loadW(1, WB_);
    loadB(1, B1);
    LGKM0_BARRIER();          // w_s[0] visible; B0/B1/WB_ still in flight

    #pragma unroll 1
    for (int kb = 0; kb < 13; ++kb) {
        int k = kb * 2;
        // half A: compute k (buf0,B0); stage W(k+1); prefetch (k+2)
        mfma_phase(w_s[0], B0);
        writeW(1, WB_);                       // W(k+1) -> buf1
        {
            int kc = (k + 2 < KK) ? k + 2 : KK - 1;
            loadW(kc, WA);
            loadB(kc, B0);
        }
        LGKM0_BARRIER();

        // half B: compute k+1 (buf1,B1); stage W(k+2); prefetch (k+3)
        mfma_phase(w_s[1], B1);
        writeW(0, WA);                        // W(k+2) -> buf0
        {
            int kc = (k + 3 < KK) ? k + 3 : KK - 1;
            loadW(kc, WB_);
            loadB(kc, B1);
        }
        LGKM0_BARRIER();
    }
    mfma_phase(w_s[0], B0);                   // k = 26

    // ---- epilogue: D row = quad*4+r (o), col (h); relu + fp32 store ----
    #pragma unroll
    for (int mt = 0; mt < 8; ++mt) {
        #pragma unroll
        for (int nt = 0; nt < 4; ++nt) {
            int hg = hbase + wave * 64 + nt * 16 + col;
            if (hg < HH) {
                #pragma unroll
                for (int r = 0; r < 4; ++r) {
                    int o = mt * 16 + quad * 4 + r;
                    float v = acc[mt][nt][r];
                    out[(size_t)o * HH + hg] = v > 0.f ? v : 0.f;
                }
            }
        }
    }
}

extern "C" void kernel_launch(void* const* d_in, const int* in_sizes, int n_in,
                              void* d_out, int out_size, void* d_ws, size_t ws_size,
                              hipStream_t stream) {
    const float* data_in = (const float*)d_in[0];
    const int*   neigh   = (const int*)d_in[1];
    const float* weight  = (const float*)d_in[2];
    float* out = (float*)d_out;

    unsigned short* xt = (unsigned short*)d_ws;            // H*64 bf16 = 12.8 MB
    unsigned short* wk = xt + (size_t)HH * 64;             // 27*128*64 bf16 = 442 KB

    prep_kernel<<<TB + WB, 256, 0, stream>>>(data_in, weight, xt, wk);
    conv_main<<<NBLK, 256, 0, stream>>>(xt, wk, neigh, out);
}

// Round 7
// 198.011 us; speedup vs baseline: 1.5914x; 1.1752x over previous
//
#include <hip/hip_runtime.h>
#include <hip/hip_bf16.h>

#define C_IN  64
#define C_OUT 128
#define KK    27
#define HH    100000
#define TB    1563         // transpose blocks = ceil(HH/64)
#define WB    108          // weight-convert blocks (108*2048 = 221184 elems)
#define NBLK  391          // ceil(HH/256)

typedef __attribute__((ext_vector_type(8))) short s8v;    // 8 bf16 (MFMA A/B frag)
typedef __attribute__((ext_vector_type(4))) float f32x4;  // MFMA C/D frag

// Non-draining pipeline barrier: s_waitcnt vmcnt(8) lgkmcnt(0); s_barrier.
// imm encoding: vmcnt[3:0]=8, expcnt=7 (ignore), lgkmcnt=0, vmcnt[5:4]=0 -> 0x0078.
// Retires the 4 oldest outstanding loads (the W DMAs) while leaving the 8
// B-gather prefetches in flight ACROSS the barrier.
#define PIPE_BARRIER() do { \
    __asm__ __volatile__("" ::: "memory"); \
    __builtin_amdgcn_s_waitcnt(0x0078); \
    __builtin_amdgcn_s_barrier(); \
    __asm__ __volatile__("" ::: "memory"); \
} while (0)

__device__ inline unsigned short f2bf(float f) {
    __hip_bfloat16 h = __float2bfloat16(f);
    return *reinterpret_cast<unsigned short*>(&h);
}

__device__ inline void dma16(const void* g, void* l) {
    __builtin_amdgcn_global_load_lds((const __attribute__((address_space(1))) void*)g,
                                     (__attribute__((address_space(3))) void*)l, 16, 0, 0);
}

// ---- prep: transpose x -> xt (bf16, [h][64]), W -> wk (bf16, [k][o][64] XOR-swizzled) ----
// wk physical chunk pj (16B unit) holds logical chunk pj ^ (o&7).
__global__ __launch_bounds__(256) void prep_kernel(const float* __restrict__ x,
                                                   const float* __restrict__ w,
                                                   unsigned short* __restrict__ xt,
                                                   unsigned short* __restrict__ wk) {
    const int tid = threadIdx.x;
    if (blockIdx.x < TB) {
        __shared__ __align__(16) unsigned short ts[64 * 72];
        const int hbase = blockIdx.x * 64;
        #pragma unroll
        for (int it = 0; it < 16; ++it) {
            int i = it * 256 + tid;           // 64h x 64c
            int c = i >> 6, hl = i & 63;
            int hg = hbase + hl;
            float v = (hg < HH) ? x[(size_t)c * HH + hg] : 0.f;  // coalesced in h
            ts[hl * 72 + c] = f2bf(v);
        }
        __syncthreads();
        #pragma unroll
        for (int it = 0; it < 2; ++it) {
            int u = it * 256 + tid;           // 64 rows x 8 chunks of 16B
            int hl = u >> 3, part = u & 7;
            int hg = hbase + hl;
            if (hg < HH)
                *(int4*)&xt[(size_t)hg * 64 + part * 8] = *(const int4*)&ts[hl * 72 + part * 8];
        }
    } else {
        int b = blockIdx.x - TB;
        int base = b * 2048 + tid;
        #pragma unroll
        for (int j = 0; j < 8; ++j) {
            int t = base + j * 256;           // wk index: t = k*8192 + o*64 + jj
            int jj = t & 63, o = (t >> 6) & 127, kx = t >> 13;
            int lc = (jj >> 3) ^ (o & 7);     // logical chunk
            int c  = lc * 8 + (jj & 7);
            wk[t] = f2bf(w[(size_t)o * (C_IN * KK) + c * KK + kx]);
        }
    }
}

// ---------------- main gather-GEMM ----------------
// block 256 thr = 4 waves; wave tile M=128 (all o) x N=64 h.
// W via async DMA double-buffered LDS; B direct global->VGPR, depth-1 ping-pong.
// K-loop barriers are non-draining (vmcnt(8)): B prefetches survive the barrier.
__global__ __launch_bounds__(256, 2) void conv_main(const unsigned short* __restrict__ xt,
                                                    const unsigned short* __restrict__ wk,
                                                    const int* __restrict__ neigh,
                                                    float* __restrict__ out) {
    __shared__ int neigh_s[256 * KK];                            // 27648 B, [h][k]
    __shared__ __align__(16) unsigned short w_s[2][128 * 64];    // 2 x 16 KB, XOR-swizzled rows

    const int tid  = threadIdx.x;
    const int wave = tid >> 6;
    const int lane = tid & 63;
    const int col  = lane & 15;
    const int quad = lane >> 4;
    const int hbase = blockIdx.x * 256;

    // ---- stage neighbor indices (coalesced; 27*256 exactly) ----
    #pragma unroll
    for (int j = 0; j < KK; ++j) {
        int i = j * 256 + tid;
        int hl = i / KK, kx = i - hl * KK;
        int hg = hbase + hl;
        neigh_s[i] = (hg < HH) ? neigh[(size_t)hg * KK + kx] : -1;
    }

    // ---- W DMA issue helper: 16 KB slice k -> w_s[b] (4 insts/wave, contiguous) ----
    auto dmaW = [&](int k, int b) {
        const unsigned short* src = wk + (size_t)k * (C_OUT * C_IN);
        #pragma unroll
        for (int i = 0; i < 4; ++i) {
            int row_base = wave * 8 + i * 32;   // 8 rows = 1024 B per inst per wave
            dma16(src + row_base * 64 + lane * 8, &w_s[b][row_base * 64]);
        }
    };

    dmaW(0, 0);

    f32x4 acc[8][4];
    #pragma unroll
    for (int mt = 0; mt < 8; ++mt)
        #pragma unroll
        for (int nt = 0; nt < 4; ++nt)
            acc[mt][nt] = (f32x4){0.f, 0.f, 0.f, 0.f};

    __syncthreads();   // once: neigh_s visible + DMA(0) drained (full drain OK here)

    const unsigned short* xq = xt + quad * 8;   // lane's chunk base within a gathered column

    auto loadB = [&](int kk, int4 (&B)[2][4]) {
        #pragma unroll
        for (int nt = 0; nt < 4; ++nt) {
            int n = wave * 64 + nt * 16 + col;
            int idx = neigh_s[n * KK + kk];
            if (idx >= 0) {
                const unsigned short* base = xq + (size_t)idx * 64;
                B[0][nt] = *(const int4*)(base);        // c in [quad*8, quad*8+8)
                B[1][nt] = *(const int4*)(base + 32);   // c + 32
            } else {
                B[0][nt] = make_int4(0, 0, 0, 0);
                B[1][nt] = make_int4(0, 0, 0, 0);
            }
        }
    };

    auto mfma_phase = [&](const unsigned short* wbuf, int4 (&B)[2][4]) {
        #pragma unroll
        for (int ch = 0; ch < 2; ++ch) {
            const int pc = (ch * 4 + quad) ^ (col & 7);   // XOR-swizzled physical chunk
            #pragma unroll
            for (int mt = 0; mt < 8; ++mt) {
                s8v a = *(const s8v*)&wbuf[(mt * 16 + col) * 64 + pc * 8];
                #pragma unroll
                for (int nt = 0; nt < 4; ++nt)
                    acc[mt][nt] = __builtin_amdgcn_mfma_f32_16x16x32_bf16(
                        a, __builtin_bit_cast(s8v, B[ch][nt]), acc[mt][nt], 0, 0, 0);
            }
        }
    };

    int4 B0[2][4], B1[2][4];
    loadB(0, B0);

    // 27 = 13*2 + 1; ping-pong (B0,buf0)/(B1,buf1); non-draining barriers
    #pragma unroll 1
    for (int kb = 0; kb < 13; ++kb) {
        int k = kb * 2;
        dmaW(k + 1, 1);                  // 4 DMA (oldest in queue)
        loadB(k + 1, B1);                // 8 gathers (stay in flight across barrier)
        mfma_phase(w_s[0], B0);
        PIPE_BARRIER();                  // vmcnt(8): DMA k+1 done, B(k+1) still flying

        if (k + 2 < KK) {
            dmaW(k + 2, 0);
            loadB(k + 2, B0);
        }
        mfma_phase(w_s[1], B1);
        PIPE_BARRIER();                  // vmcnt(8): DMA k+2 done, B(k+2) still flying
    }
    mfma_phase(w_s[0], B0);              // k = 26

    // ---- epilogue: D row = quad*4+r (o), col (h); relu + non-temporal fp32 store ----
    #pragma unroll
    for (int mt = 0; mt < 8; ++mt) {
        #pragma unroll
        for (int nt = 0; nt < 4; ++nt) {
            int hg = hbase + wave * 64 + nt * 16 + col;
            if (hg < HH) {
                #pragma unroll
                for (int r = 0; r < 4; ++r) {
                    int o = mt * 16 + quad * 4 + r;
                    float v = acc[mt][nt][r];
                    v = v > 0.f ? v : 0.f;
                    __builtin_nontemporal_store(v, &out[(size_t)o * HH + hg]);
                }
            }
        }
    }
}

extern "C" void kernel_launch(void* const* d_in, const int* in_sizes, int n_in,
                              void* d_out, int out_size, void* d_ws, size_t ws_size,
                              hipStream_t stream) {
    const float* data_in = (const float*)d_in[0];
    const int*   neigh   = (const int*)d_in[1];
    const float* weight  = (const float*)d_in[2];
    float* out = (float*)d_out;

    unsigned short* xt = (unsigned short*)d_ws;            // H*64 bf16 = 12.8 MB
    unsigned short* wk = xt + (size_t)HH * 64;             // 27*128*64 bf16 = 442 KB

    prep_kernel<<<TB + WB, 256, 0, stream>>>(data_in, weight, xt, wk);
    conv_main<<<NBLK, 256, 0, stream>>>(xt, wk, neigh, out);
}